// Round 17
// baseline (152.434 us; speedup 1.0000x reference)
//
#include <hip/hip_runtime.h>
#include <hip/hip_bf16.h>

#define NQH 64
#define NKVH 8
#define DH 64
#define SEQ 1024
#define HID 2880
#define QKV_N 5120   // (NQ+2*NKV)*DH
#define ATTN_N 4096  // NQ*DH
#define WIN 128
#define WO_NPAD 2880 // 30*96 exactly — no padding needed
#define SCALE_F 0.125f

typedef __attribute__((ext_vector_type(8))) __bf16 bf16x8;
typedef __attribute__((ext_vector_type(4))) float f32x4;

#define GLOAD_LDS16(g, l) \
    __builtin_amdgcn_global_load_lds((const __attribute__((address_space(1))) void*)(g), \
                                     (__attribute__((address_space(3))) void*)(l), 16, 0, 0)

__device__ __forceinline__ ushort f2bf(float x) {
    union { float f; unsigned int u; } c; c.f = x;
    unsigned int u = c.u;
    unsigned int r = (u + 0x7FFFu + ((u >> 16) & 1u)) >> 16;
    return (ushort)r;
}

template<int N>
__device__ __forceinline__ void wait_vm() {
    static_assert(N >= 0 && N <= 6, "extend wait_vm");
    if constexpr (N == 0) asm volatile("s_waitcnt vmcnt(0)" ::: "memory");
    else if constexpr (N == 1) asm volatile("s_waitcnt vmcnt(1)" ::: "memory");
    else if constexpr (N == 2) asm volatile("s_waitcnt vmcnt(2)" ::: "memory");
    else if constexpr (N == 3) asm volatile("s_waitcnt vmcnt(3)" ::: "memory");
    else if constexpr (N == 4) asm volatile("s_waitcnt vmcnt(4)" ::: "memory");
    else if constexpr (N == 5) asm volatile("s_waitcnt vmcnt(5)" ::: "memory");
    else asm volatile("s_waitcnt vmcnt(6)" ::: "memory");
}

// ---------------------------------------------------------------- convert (plain)
__global__ __launch_bounds__(256) void convert_f32_bf16(
    const float* __restrict__ in, ushort* __restrict__ out, int n4)
{
    int idx = blockIdx.x * blockDim.x + threadIdx.x;
    int stride = gridDim.x * blockDim.x;
    for (int i = idx; i < n4; i += stride) {
        float4 v = reinterpret_cast<const float4*>(in)[i];
        ushort4 o;
        o.x = f2bf(v.x); o.y = f2bf(v.y); o.z = f2bf(v.z); o.w = f2bf(v.w);
        reinterpret_cast<ushort4*>(out)[i] = o;
    }
}

// ---------------------------------------------------------------- transpose+convert
// in: [K][N] f32  ->  out: [Npad][K] bf16 (rows >= N zero-filled). K,Npad multiples of 64.
__global__ __launch_bounds__(256) void transpose_convert(
    const float* __restrict__ in, ushort* __restrict__ out, int K, int N)
{
    __shared__ ushort tile[64][80];   // row stride 160B (16B-aligned for uint4)
    const int bk = blockIdx.x * 64;   // k tile origin
    const int bn = blockIdx.y * 64;   // n tile origin
    const int tid = threadIdx.x;
    const bool inb = bn < N;          // whole tile valid or whole tile pad (N % 64 == 0)

#pragma unroll
    for (int it = 0; it < 4; ++it) {
        int r = it * 16 + (tid >> 4);         // k offset 0..63
        int c4 = (tid & 15) * 4;              // n offset
        float4 v = make_float4(0.f, 0.f, 0.f, 0.f);
        if (inb) v = *(const float4*)&in[(size_t)(bk + r) * N + bn + c4];
        tile[c4 + 0][r] = f2bf(v.x);
        tile[c4 + 1][r] = f2bf(v.y);
        tile[c4 + 2][r] = f2bf(v.z);
        tile[c4 + 3][r] = f2bf(v.w);
    }
    __syncthreads();
#pragma unroll
    for (int it = 0; it < 2; ++it) {
        int nr = it * 32 + (tid >> 3);        // n offset 0..63
        int c8 = (tid & 7) * 8;               // k offset
        uint4 v = *(const uint4*)&tile[nr][c8];
        *(uint4*)&out[(size_t)(bn + nr) * K + bk + c8] = v;
    }
}

// ---------------------------------------------------------------- big-tile counted-vmcnt GEMM, BK=64
// A: [M][K] bf16, BT: [Npad][K] bf16, C: [M][ldC] f32 (+bias), K % 64 == 0.
// R16 post-mortem: at 1 block/CU the __syncthreads vmcnt(0)-drain exposes ~1550 cyc/step
// (measured 3157 cyc/step vs 1600 port-model). Here the step window (1600 cyc) EXCEEDS
// HBM latency (~900), so a depth-1 prefetch surviving the barrier hides it — the regime
// R7's counted-vmcnt needed. Sync per step: STAGE(next) -> vmcnt(NFULL) -> s_barrier ->
// COMPUTE -> lgkmcnt(0) -> s_barrier. vmcnt(NFULL) is conservative-uniform (partial last
// staging round is wave-uniform; oldest-first retirement makes <=1 over-wait safe).
// Tiles: gemm1 128x160 (57 B/KFLOP), gemm2 128x96 (69) — grids 256 / 240, ~1 block/CU.
template<int BM, int BN, int WAVES_N>
__global__ __launch_bounds__(512) void gemm_cv(
    const ushort* __restrict__ A, const ushort* __restrict__ BT,
    const float* __restrict__ bias, float* __restrict__ C,
    int K, int ldC, int Nreal)
{
    constexpr int WAVES_M = 8 / WAVES_N;
    constexpr int WM = BM / WAVES_M;
    constexpr int WN = BN / WAVES_N;
    constexpr int MR = WM / 16;
    constexpr int NR = WN / 16;
    constexpr int ASZ = BM * 64;          // elements per buffer
    constexpr int BSZ = BN * 64;
    constexpr int ACH = BM * 8;           // 16B chunks in A tile
    constexpr int TOTCH = (BM + BN) * 8;
    constexpr int NLOAD = (TOTCH + 511) / 512;
    constexpr int NFULL = TOTCH / 512;    // per-wave guaranteed loads per stage

    __shared__ ushort Al[2 * ASZ];
    __shared__ ushort Bl[2 * BSZ];

    const int t = threadIdx.x;
    const int lane = t & 63;
    const int w = t >> 6;
    const int wr = w / WAVES_N;
    const int wc = w % WAVES_N;
    const int g4 = lane >> 4;
    const int r15 = lane & 15;

    // bijective XCD swizzle (nwg % 8 == 0); n-tiles walk fastest within an XCD
    const int nx = gridDim.x;
    const int flat = blockIdx.x + nx * blockIdx.y;
    const int per = (nx * gridDim.y) >> 3;
    const int virt = (flat & 7) * per + (flat >> 3);
    const int n0 = (virt % nx) * BN;
    const int m0 = (virt / nx) * BM;

    // ---- staging tables (inverse-swizzled global source, linear LDS dest)
    const ushort* src[NLOAD];
    ushort* d0[NLOAD];
    ushort* d1[NLOAD];
#pragma unroll
    for (int i = 0; i < NLOAD; ++i) {
        int lin = i * 512 + t;
        src[i] = nullptr; d0[i] = nullptr; d1[i] = nullptr;
        if (lin < ACH) {
            int row = lin >> 3, ch = (lin & 7) ^ (row & 7);
            src[i] = A + (size_t)(m0 + row) * K + ch * 8;
            d0[i] = &Al[lin * 8];
            d1[i] = &Al[ASZ + lin * 8];
        } else if (lin < TOTCH) {
            int l2 = lin - ACH;
            int row = l2 >> 3, ch = (l2 & 7) ^ (row & 7);
            src[i] = BT + (size_t)(n0 + row) * K + ch * 8;
            d0[i] = &Bl[l2 * 8];
            d1[i] = &Bl[BSZ + l2 * 8];
        }
    }

#define STAGE_TILE(buf) do { \
        _Pragma("unroll") \
        for (int i = 0; i < NLOAD; ++i) \
            if (src[i]) { \
                GLOAD_LDS16(src[i], (buf) ? d1[i] : d0[i]); \
                src[i] += 64; \
            } \
    } while (0)

    // ---- fragment read offsets (element units), swizzled to match staging
    int aoff[MR][2], boff[NR][2];
#pragma unroll
    for (int mi = 0; mi < MR; ++mi)
#pragma unroll
        for (int ks = 0; ks < 2; ++ks) {
            int row = wr * WM + mi * 16 + r15;
            aoff[mi][ks] = row * 64 + (((ks * 4 + g4) ^ (row & 7)) * 8);
        }
#pragma unroll
    for (int ni = 0; ni < NR; ++ni)
#pragma unroll
        for (int ks = 0; ks < 2; ++ks) {
            int col = wc * WN + ni * 16 + r15;
            boff[ni][ks] = col * 64 + (((ks * 4 + g4) ^ (col & 7)) * 8);
        }

    f32x4 acc[MR][NR];
#pragma unroll
    for (int mi = 0; mi < MR; ++mi)
#pragma unroll
        for (int ni = 0; ni < NR; ++ni) acc[mi][ni] = (f32x4){0.f, 0.f, 0.f, 0.f};

#define COMPUTE_TILE(buf) do { \
        const ushort* Ab = &Al[(buf) * ASZ]; \
        const ushort* Bb = &Bl[(buf) * BSZ]; \
        _Pragma("unroll") \
        for (int ks = 0; ks < 2; ++ks) { \
            bf16x8 af[MR], bfr[NR]; \
            _Pragma("unroll") \
            for (int mi = 0; mi < MR; ++mi) af[mi] = *(const bf16x8*)&Ab[aoff[mi][ks]]; \
            _Pragma("unroll") \
            for (int ni = 0; ni < NR; ++ni) bfr[ni] = *(const bf16x8*)&Bb[boff[ni][ks]]; \
            _Pragma("unroll") \
            for (int mi = 0; mi < MR; ++mi) \
                _Pragma("unroll") \
                for (int ni = 0; ni < NR; ++ni) \
                    acc[mi][ni] = __builtin_amdgcn_mfma_f32_16x16x32_bf16(af[mi], bfr[ni], acc[mi][ni], 0, 0, 0); \
        } \
    } while (0)

    const int NT = K >> 6;
    STAGE_TILE(0);                              // tile 0 in flight (never drained to 0)
    for (int kt = 0; kt < NT; kt += 2) {
        // ---- even step: compute buf0 (tile kt)
        if (kt + 1 < NT) {
            STAGE_TILE(1);                      // tile kt+1 in flight behind tile kt
            wait_vm<NFULL>();                   // oldest batch (tile kt) retired
        } else {
            wait_vm<0>();
        }
        __builtin_amdgcn_s_barrier();
        __builtin_amdgcn_sched_barrier(0);
        COMPUTE_TILE(0);
        asm volatile("s_waitcnt lgkmcnt(0)" ::: "memory");
        __builtin_amdgcn_sched_barrier(0);
        __builtin_amdgcn_s_barrier();           // buf0 free for restage
        // ---- odd step: compute buf1 (tile kt+1)
        if (kt + 1 < NT) {
            if (kt + 2 < NT) {
                STAGE_TILE(0);
                wait_vm<NFULL>();
            } else {
                wait_vm<0>();
            }
            __builtin_amdgcn_s_barrier();
            __builtin_amdgcn_sched_barrier(0);
            COMPUTE_TILE(1);
            asm volatile("s_waitcnt lgkmcnt(0)" ::: "memory");
            __builtin_amdgcn_sched_barrier(0);
            __builtin_amdgcn_s_barrier();
        }
    }
#undef STAGE_TILE
#undef COMPUTE_TILE

    // ---- epilogue: bias, f32 store (rope fused into attention)
    // D frag: row = g4*4 + r (+16*mi +WM*wr +m0), col = r15 (+16*ni +WN*wc +n0)
#pragma unroll
    for (int ni = 0; ni < NR; ++ni) {
        int col = n0 + wc * WN + ni * 16 + r15;
        if (col < Nreal) {
            float bv = bias[col];
#pragma unroll
            for (int mi = 0; mi < MR; ++mi) {
                int row = m0 + wr * WM + mi * 16 + g4 * 4;
#pragma unroll
                for (int r = 0; r < 4; ++r)
                    C[(size_t)(row + r) * ldC + col] = acc[mi][ni][r] + bv;
            }
        }
    }
}

// ---------------------------------------------------------------- MFMA flash attention (+fused RoPE)
// qkv holds RAW (bias-added, un-roped) q,k,v. RoPE applied here in f32 during bf16 convert.
__global__ __launch_bounds__(512) void attn_mfma_kernel(
    const float* __restrict__ qkv, const float* __restrict__ sinks,
    const float* __restrict__ cosp, const float* __restrict__ sinp,
    ushort* __restrict__ attn_out)
{
    __shared__ __align__(16) ushort Kl[160][72];    // [key][d], pad 64->72 (2-way free)
    __shared__ __align__(16) ushort Vt[64][168];    // [d][key], pad 160->168 (2-way free)
    __shared__ __align__(16) ushort Pl[8][32][40];  // per-wave P chunk [row][32 keys], pad->40
    const int t = threadIdx.x;
    const int w = t >> 6;
    const int l = t & 63;
    const int g4 = l >> 4;
    const int r15 = l & 15;
    const int q0 = blockIdx.x * 32;
    const int hk = blockIdx.y;
    const int kbase = q0 - 128;

    // ---- stage K (rope'd) [160][64] f32->bf16 and V^T [64][160]
#pragma unroll
    for (int i = 0; i < 5; ++i) {
        int idx = i * 512 + t;             // 0..2559
        int row = idx >> 4;                // 0..159
        int c4 = (idx & 15) * 4;           // 0..60
        int j = kbase + row;
        float4 kr = make_float4(0.f, 0.f, 0.f, 0.f);
        float4 vv = make_float4(0.f, 0.f, 0.f, 0.f);
        if (j >= 0) {
            const float* kb = &qkv[(size_t)j * QKV_N + 4096 + hk * 64];
            float4 kx = *(const float4*)&kb[c4];
            float4 ky = *(const float4*)&kb[c4 ^ 32];
            float4 cs = *(const float4*)&cosp[j * 32 + (c4 & 31)];
            float4 sn = *(const float4*)&sinp[j * 32 + (c4 & 31)];
            if (c4 < 32) {
                kr.x = kx.x * cs.x - ky.x * sn.x; kr.y = kx.y * cs.y - ky.y * sn.y;
                kr.z = kx.z * cs.z - ky.z * sn.z; kr.w = kx.w * cs.w - ky.w * sn.w;
            } else {
                kr.x = kx.x * cs.x + ky.x * sn.x; kr.y = kx.y * cs.y + ky.y * sn.y;
                kr.z = kx.z * cs.z + ky.z * sn.z; kr.w = kx.w * cs.w + ky.w * sn.w;
            }
            vv = *(const float4*)&qkv[(size_t)j * QKV_N + 4608 + hk * 64 + c4];
        }
        ushort4 kp;
        kp.x = f2bf(kr.x); kp.y = f2bf(kr.y); kp.z = f2bf(kr.z); kp.w = f2bf(kr.w);
        *(ushort4*)&Kl[row][c4] = kp;
        Vt[c4 + 0][row] = f2bf(vv.x);
        Vt[c4 + 1][row] = f2bf(vv.y);
        Vt[c4 + 2][row] = f2bf(vv.z);
        Vt[c4 + 3][row] = f2bf(vv.w);
    }

    // ---- Q fragments, rope'd (B operand: lane supplies col = score-row = r15+16ct, k = d)
    bf16x8 qf[2][2];
#pragma unroll
    for (int ct = 0; ct < 2; ++ct) {
        int R = w * 32 + ct * 16 + r15;
        int q = q0 + (R & 31);
        int hq = hk * 8 + (R >> 5);
        const float* qb = &qkv[(size_t)q * QKV_N + hq * 64];
        int d8 = g4 * 8;                       // 0,8,16,24 (first-half base)
        float4 a0 = *(const float4*)&qb[d8];          // s=0 lo
        float4 b0 = *(const float4*)&qb[d8 + 4];      // s=0 hi
        float4 a1 = *(const float4*)&qb[32 + d8];     // s=1 lo
        float4 b1 = *(const float4*)&qb[32 + d8 + 4]; // s=1 hi
        float4 c0 = *(const float4*)&cosp[q * 32 + d8];
        float4 c1 = *(const float4*)&cosp[q * 32 + d8 + 4];
        float4 s0 = *(const float4*)&sinp[q * 32 + d8];
        float4 s1 = *(const float4*)&sinp[q * 32 + d8 + 4];
        union { ushort u[8]; bf16x8 v; } p0, p1;
        p0.u[0] = f2bf((a0.x * c0.x - a1.x * s0.x) * SCALE_F);
        p0.u[1] = f2bf((a0.y * c0.y - a1.y * s0.y) * SCALE_F);
        p0.u[2] = f2bf((a0.z * c0.z - a1.z * s0.z) * SCALE_F);
        p0.u[3] = f2bf((a0.w * c0.w - a1.w * s0.w) * SCALE_F);
        p0.u[4] = f2bf((b0.x * c1.x - b1.x * s1.x) * SCALE_F);
        p0.u[5] = f2bf((b0.y * c1.y - b1.y * s1.y) * SCALE_F);
        p0.u[6] = f2bf((b0.z * c1.z - b1.z * s1.z) * SCALE_F);
        p0.u[7] = f2bf((b0.w * c1.w - b1.w * s1.w) * SCALE_F);
        p1.u[0] = f2bf((a1.x * c0.x + a0.x * s0.x) * SCALE_F);
        p1.u[1] = f2bf((a1.y * c0.y + a0.y * s0.y) * SCALE_F);
        p1.u[2] = f2bf((a1.z * c0.z + a0.z * s0.z) * SCALE_F);
        p1.u[3] = f2bf((a1.w * c0.w + a0.w * s0.w) * SCALE_F);
        p1.u[4] = f2bf((b1.x * c1.x + b0.x * s1.x) * SCALE_F);
        p1.u[5] = f2bf((b1.y * c1.y + b0.y * s1.y) * SCALE_F);
        p1.u[6] = f2bf((b1.z * c1.z + b0.z * s1.z) * SCALE_F);
        p1.u[7] = f2bf((b1.w * c1.w + b0.w * s1.w) * SCALE_F);
        qf[ct][0] = p0.v;
        qf[ct][1] = p1.v;
    }
    __syncthreads();

    // ---- S^T = K @ Q^T : D row = key = 16kt+4g4+r, col = score-row = 16ct+r15 (+32w)
    f32x4 sc[10][2];
#pragma unroll
    for (int kt = 0; kt < 10; ++kt) {
        sc[kt][0] = (f32x4){0.f, 0.f, 0.f, 0.f};
        sc[kt][1] = (f32x4){0.f, 0.f, 0.f, 0.f};
    }
#pragma unroll
    for (int kt = 0; kt < 10; ++kt) {
#pragma unroll
        for (int s = 0; s < 2; ++s) {
            bf16x8 kf = *(const bf16x8*)&Kl[kt * 16 + r15][s * 32 + g4 * 8];
            sc[kt][0] = __builtin_amdgcn_mfma_f32_16x16x32_bf16(kf, qf[0][s], sc[kt][0], 0, 0, 0);
            sc[kt][1] = __builtin_amdgcn_mfma_f32_16x16x32_bf16(kf, qf[1][s], sc[kt][1], 0, 0, 0);
        }
    }

    // ---- masked softmax, per score-row; fold sink and 1/denom (all lane-local)
    const int minkey = 128 - q0;          // key_local >= minkey  <=>  j >= 0
#pragma unroll
    for (int ct = 0; ct < 2; ++ct) {
        int R = w * 32 + ct * 16 + r15;
        int ql = R & 31;
        float snk = sinks[hk * 8 + (R >> 5)];
#pragma unroll
        for (int kt = 0; kt < 10; ++kt)
#pragma unroll
            for (int r = 0; r < 4; ++r) {
                int key = kt * 16 + g4 * 4 + r;
                // allowed: q_local < key <= q_local+128 (window+causal), key >= minkey (j>=0)
                bool ok = (key > ql) && (key <= ql + 128) && (key >= minkey);
                if (!ok) sc[kt][ct][r] = -1e30f;
            }
        float m = snk;
#pragma unroll
        for (int kt = 0; kt < 10; ++kt)
#pragma unroll
            for (int r = 0; r < 4; ++r) m = fmaxf(m, sc[kt][ct][r]);
        m = fmaxf(m, __shfl_xor(m, 16));
        m = fmaxf(m, __shfl_xor(m, 32));
        float sum = 0.f;
#pragma unroll
        for (int kt = 0; kt < 10; ++kt)
#pragma unroll
            for (int r = 0; r < 4; ++r) {
                float p = __expf(sc[kt][ct][r] - m);
                sc[kt][ct][r] = p;
                sum += p;
            }
        sum += __shfl_xor(sum, 16);
        sum += __shfl_xor(sum, 32);
        sum += __expf(snk - m);
        float iv = 1.0f / sum;
#pragma unroll
        for (int kt = 0; kt < 10; ++kt)
#pragma unroll
            for (int r = 0; r < 4; ++r) sc[kt][ct][r] *= iv;
    }

    // ---- PV: out[row][d] = sum_key P[row][key] * V[key][d]
    f32x4 pv[2][4];
#pragma unroll
    for (int mi = 0; mi < 2; ++mi)
#pragma unroll
        for (int ni = 0; ni < 4; ++ni) pv[mi][ni] = (f32x4){0.f, 0.f, 0.f, 0.f};

#pragma unroll
    for (int s = 0; s < 5; ++s) {
#pragma unroll
        for (int ct = 0; ct < 2; ++ct)
#pragma unroll
            for (int kh = 0; kh < 2; ++kh) {
                int kt = 2 * s + kh;
                ushort4 p4;
                p4.x = f2bf(sc[kt][ct][0]);
                p4.y = f2bf(sc[kt][ct][1]);
                p4.z = f2bf(sc[kt][ct][2]);
                p4.w = f2bf(sc[kt][ct][3]);
                *(ushort4*)&Pl[w][ct * 16 + r15][kh * 16 + g4 * 4] = p4;
            }
#pragma unroll
        for (int mi = 0; mi < 2; ++mi) {
            bf16x8 pf = *(const bf16x8*)&Pl[w][mi * 16 + r15][g4 * 8];
#pragma unroll
            for (int ni = 0; ni < 4; ++ni) {
                bf16x8 vf = *(const bf16x8*)&Vt[ni * 16 + r15][s * 32 + g4 * 8];
                pv[mi][ni] = __builtin_amdgcn_mfma_f32_16x16x32_bf16(pf, vf, pv[mi][ni], 0, 0, 0);
            }
        }
    }

    // ---- write attn output (bf16): D row = 16mi+4g4+r (+32w), col = d = 16ni+r15
#pragma unroll
    for (int mi = 0; mi < 2; ++mi)
#pragma unroll
        for (int r = 0; r < 4; ++r) {
            int R = w * 32 + mi * 16 + g4 * 4 + r;
            int q = q0 + (R & 31);
            int hq = hk * 8 + (R >> 5);
            ushort* ob = &attn_out[(size_t)q * ATTN_N + hq * 64 + r15];
#pragma unroll
            for (int ni = 0; ni < 4; ++ni)
                ob[ni * 16] = f2bf(pv[mi][ni][r]);
        }
}

// ---------------------------------------------------------------- launch
extern "C" void kernel_launch(void* const* d_in, const int* in_sizes, int n_in,
                              void* d_out, int out_size, void* d_ws, size_t ws_size,
                              hipStream_t stream)
{
    const float* hidden = (const float*)d_in[0];
    const float* cosp   = (const float*)d_in[1];
    const float* sinp   = (const float*)d_in[2];
    const float* w_qkv  = (const float*)d_in[3];
    const float* b_qkv  = (const float*)d_in[4];
    const float* w_o    = (const float*)d_in[5];
    const float* b_o    = (const float*)d_in[6];
    const float* sinks  = (const float*)d_in[7];
    // d_in[8]=k_cache, d_in[9]=v_cache (zero), d_in[10]=kv_len (==0): unused.

    char* ws = (char*)d_ws;
    size_t off = 0;
    ushort* wqkvT = (ushort*)(ws + off); off += (size_t)QKV_N * HID * 2;      // [5120][2880]
    ushort* woT   = (ushort*)(ws + off); off += (size_t)WO_NPAD * ATTN_N * 2; // [2880][4096]
    float*  qkv   = (float*)(ws + off);  off += (size_t)SEQ * QKV_N * 4;
    // union region: hidden_b (gemm1 A) then attn_b (gemm2 A) — lifetimes disjoint
    ushort* hidden_b = (ushort*)(ws + off);
    ushort* attn_b   = (ushort*)(ws + off); off += (size_t)SEQ * ATTN_N * 2;
    if (off > ws_size) return;  // fail visibly rather than corrupt

    // weight transposes + hidden convert
    transpose_convert<<<dim3(HID / 64, QKV_N / 64), 256, 0, stream>>>(w_qkv, wqkvT, HID, QKV_N);
    transpose_convert<<<dim3(ATTN_N / 64, WO_NPAD / 64), 256, 0, stream>>>(w_o, woT, ATTN_N, HID);
    convert_f32_bf16<<<2048, 256, 0, stream>>>(hidden, hidden_b, SEQ * HID / 4);

    // QKV projection (rope deferred to attention). Tile 128x160, grid 32x8 = 256 (1/CU).
    gemm_cv<128, 160, 2><<<dim3(QKV_N / 160, SEQ / 128), 512, 0, stream>>>(
        hidden_b, wqkvT, b_qkv, qkv, HID, QKV_N, QKV_N);

    // MFMA flash attention with fused RoPE on Q and K
    attn_mfma_kernel<<<dim3(SEQ / 32, NKVH), 512, 0, stream>>>(
        qkv, sinks, cosp, sinp, attn_b);

    // output projection. Tile 128x96, grid 30x8 = 240. 2880 = 30*96 exactly.
    gemm_cv<128, 96, 2><<<dim3(HID / 96, SEQ / 128), 512, 0, stream>>>(
        attn_b, woT, b_o, (float*)d_out, ATTN_N, HID, HID);
}

// Round 18
// 150.391 us; speedup vs baseline: 1.0136x; 1.0136x over previous
//
#include <hip/hip_runtime.h>
#include <hip/hip_bf16.h>

#define NQH 64
#define NKVH 8
#define DH 64
#define SEQ 1024
#define HID 2880
#define QKV_N 5120   // (NQ+2*NKV)*DH
#define ATTN_N 4096  // NQ*DH
#define WIN 128
#define WO_NPAD 2880 // 45*64 exactly
#define SCALE_F 0.125f

typedef __attribute__((ext_vector_type(8))) __bf16 bf16x8;
typedef __attribute__((ext_vector_type(4))) float f32x4;
typedef __attribute__((ext_vector_type(16))) float f32x16;

#define GLOAD_LDS16(g, l) \
    __builtin_amdgcn_global_load_lds((const __attribute__((address_space(1))) void*)(g), \
                                     (__attribute__((address_space(3))) void*)(l), 16, 0, 0)

__device__ __forceinline__ ushort f2bf(float x) {
    union { float f; unsigned int u; } c; c.f = x;
    unsigned int u = c.u;
    unsigned int r = (u + 0x7FFFu + ((u >> 16) & 1u)) >> 16;
    return (ushort)r;
}

// ---------------------------------------------------------------- convert (plain)
__global__ __launch_bounds__(256) void convert_f32_bf16(
    const float* __restrict__ in, ushort* __restrict__ out, int n4)
{
    int idx = blockIdx.x * blockDim.x + threadIdx.x;
    int stride = gridDim.x * blockDim.x;
    for (int i = idx; i < n4; i += stride) {
        float4 v = reinterpret_cast<const float4*>(in)[i];
        ushort4 o;
        o.x = f2bf(v.x); o.y = f2bf(v.y); o.z = f2bf(v.z); o.w = f2bf(v.w);
        reinterpret_cast<ushort4*>(out)[i] = o;
    }
}

// ---------------------------------------------------------------- transpose+convert
// in: [K][N] f32  ->  out: [Npad][K] bf16 (rows >= N zero-filled). K,Npad multiples of 64.
__global__ __launch_bounds__(256) void transpose_convert(
    const float* __restrict__ in, ushort* __restrict__ out, int K, int N)
{
    __shared__ ushort tile[64][80];   // row stride 160B (16B-aligned for uint4)
    const int bk = blockIdx.x * 64;   // k tile origin
    const int bn = blockIdx.y * 64;   // n tile origin
    const int tid = threadIdx.x;
    const bool inb = bn < N;          // whole tile valid or whole tile pad (N % 64 == 0)

#pragma unroll
    for (int it = 0; it < 4; ++it) {
        int r = it * 16 + (tid >> 4);         // k offset 0..63
        int c4 = (tid & 15) * 4;              // n offset
        float4 v = make_float4(0.f, 0.f, 0.f, 0.f);
        if (inb) v = *(const float4*)&in[(size_t)(bk + r) * N + bn + c4];
        tile[c4 + 0][r] = f2bf(v.x);
        tile[c4 + 1][r] = f2bf(v.y);
        tile[c4 + 2][r] = f2bf(v.z);
        tile[c4 + 3][r] = f2bf(v.w);
    }
    __syncthreads();
#pragma unroll
    for (int it = 0; it < 2; ++it) {
        int nr = it * 32 + (tid >> 3);        // n offset 0..63
        int c8 = (tid & 7) * 8;               // k offset
        uint4 v = *(const uint4*)&tile[nr][c8];
        *(uint4*)&out[(size_t)(bn + nr) * K + bk + c8] = v;
    }
}

// ---------------------------------------------------------------- 32x32-MFMA GEMM, BK=64
// A: [M][K] bf16, BT: [Npad][K] bf16, C: [M][ldC] f32 (+bias), K % 64 == 0.
// R13-R17 model: GEMM is LDS-port-bound (~93 B/cyc/CU) and needs 2 blocks/CU for drain
// cover. mfma_f32_32x32x16_bf16 delivers 2x FLOP per 16B/lane operand read -> frag-read
// bytes/FLOP halve: gemm1 128x128 = 39 B/KFLOP (was 95), gemm2 128x64 = 55 (was 109).
// A/B frag: lane row/col = l&31, k = (l>>5)*8 + j (one b128). C/D: col = lane&31,
// row = (reg&3) + 8*(reg>>2) + 4*(lane>>5), reg in [0,16)  [HW-verified m74/m101].
// Swizzle slot = chunk ^ (row&7): consecutive-8-lane group hits all 8 slots -> no conflict
// (same property as the measured-0-conflict 16x16 kernel). R13 dbuf sync.
template<int BM, int BN, int WAVES_N>
__global__ __launch_bounds__(512) void gemm32(
    const ushort* __restrict__ A, const ushort* __restrict__ BT,
    const float* __restrict__ bias, float* __restrict__ C,
    int K, int ldC, int Nreal)
{
    constexpr int WAVES_M = 8 / WAVES_N;
    constexpr int WM = BM / WAVES_M;      // multiple of 32
    constexpr int WN = BN / WAVES_N;      // multiple of 32
    constexpr int MR = WM / 32;
    constexpr int NR = WN / 32;
    constexpr int ASZ = BM * 64;          // elements per buffer
    constexpr int BSZ = BN * 64;
    constexpr int ACH = BM * 8;           // 16B chunks in A tile
    constexpr int TOTCH = (BM + BN) * 8;
    constexpr int NLOAD = (TOTCH + 511) / 512;

    __shared__ ushort Al[2 * ASZ];
    __shared__ ushort Bl[2 * BSZ];

    const int t = threadIdx.x;
    const int lane = t & 63;
    const int w = t >> 6;
    const int wr = w / WAVES_N;
    const int wc = w % WAVES_N;
    const int l31 = lane & 31;
    const int lh = lane >> 5;             // 0/1

    // bijective XCD swizzle (nwg % 8 == 0); n-tiles walk fastest within an XCD
    const int nx = gridDim.x;
    const int flat = blockIdx.x + nx * blockIdx.y;
    const int per = (nx * gridDim.y) >> 3;
    const int virt = (flat & 7) * per + (flat >> 3);
    const int n0 = (virt % nx) * BN;
    const int m0 = (virt / nx) * BM;

    // ---- staging tables (inverse-swizzled global source, linear LDS dest) — R13 path
    const ushort* src[NLOAD];
    ushort* d0[NLOAD];
    ushort* d1[NLOAD];
#pragma unroll
    for (int i = 0; i < NLOAD; ++i) {
        int lin = i * 512 + t;
        src[i] = nullptr; d0[i] = nullptr; d1[i] = nullptr;
        if (lin < ACH) {
            int row = lin >> 3, ch = (lin & 7) ^ (row & 7);
            src[i] = A + (size_t)(m0 + row) * K + ch * 8;
            d0[i] = &Al[lin * 8];
            d1[i] = &Al[ASZ + lin * 8];
        } else if (lin < TOTCH) {
            int l2 = lin - ACH;
            int row = l2 >> 3, ch = (l2 & 7) ^ (row & 7);
            src[i] = BT + (size_t)(n0 + row) * K + ch * 8;
            d0[i] = &Bl[l2 * 8];
            d1[i] = &Bl[BSZ + l2 * 8];
        }
    }

#define STAGE_TILE(buf) do { \
        _Pragma("unroll") \
        for (int i = 0; i < NLOAD; ++i) \
            if (src[i]) { \
                GLOAD_LDS16(src[i], (buf) ? d1[i] : d0[i]); \
                src[i] += 64; \
            } \
    } while (0)

    // ---- fragment read offsets (element units): k-frag ks (0..3), chunk = ks*2 + lh
    int aoff[MR][4], boff[NR][4];
#pragma unroll
    for (int mi = 0; mi < MR; ++mi)
#pragma unroll
        for (int ks = 0; ks < 4; ++ks) {
            int row = wr * WM + mi * 32 + l31;
            aoff[mi][ks] = row * 64 + (((ks * 2 + lh) ^ (row & 7)) * 8);
        }
#pragma unroll
    for (int ni = 0; ni < NR; ++ni)
#pragma unroll
        for (int ks = 0; ks < 4; ++ks) {
            int col = wc * WN + ni * 32 + l31;
            boff[ni][ks] = col * 64 + (((ks * 2 + lh) ^ (col & 7)) * 8);
        }

    f32x16 acc[MR][NR];
#pragma unroll
    for (int mi = 0; mi < MR; ++mi)
#pragma unroll
        for (int ni = 0; ni < NR; ++ni)
#pragma unroll
            for (int r = 0; r < 16; ++r) acc[mi][ni][r] = 0.f;

#define COMPUTE_TILE(buf) do { \
        const ushort* Ab = &Al[(buf) * ASZ]; \
        const ushort* Bb = &Bl[(buf) * BSZ]; \
        _Pragma("unroll") \
        for (int ks = 0; ks < 4; ++ks) { \
            bf16x8 af[MR], bfr[NR]; \
            _Pragma("unroll") \
            for (int mi = 0; mi < MR; ++mi) af[mi] = *(const bf16x8*)&Ab[aoff[mi][ks]]; \
            _Pragma("unroll") \
            for (int ni = 0; ni < NR; ++ni) bfr[ni] = *(const bf16x8*)&Bb[boff[ni][ks]]; \
            _Pragma("unroll") \
            for (int mi = 0; mi < MR; ++mi) \
                _Pragma("unroll") \
                for (int ni = 0; ni < NR; ++ni) \
                    acc[mi][ni] = __builtin_amdgcn_mfma_f32_32x32x16_bf16(af[mi], bfr[ni], acc[mi][ni], 0, 0, 0); \
        } \
    } while (0)

    const int NT = K >> 6;
    STAGE_TILE(0);
    __syncthreads();                            // tile 0 ready
    for (int kt = 0; kt < NT; kt += 2) {
        if (kt + 1 < NT) STAGE_TILE(1);         // prefetch next before compute
        COMPUTE_TILE(0);
        __syncthreads();
        if (kt + 1 < NT) {
            if (kt + 2 < NT) STAGE_TILE(0);
            COMPUTE_TILE(1);
            __syncthreads();
        }
    }
#undef STAGE_TILE
#undef COMPUTE_TILE

    // ---- epilogue: bias, f32 store (rope fused into attention)
    // D: col = l31 (+32*ni +WN*wc +n0), row = (reg&3)+8*(reg>>2)+4*lh (+32*mi +WM*wr +m0)
#pragma unroll
    for (int ni = 0; ni < NR; ++ni) {
        int col = n0 + wc * WN + ni * 32 + l31;
        if (col < Nreal) {
            float bv = bias[col];
#pragma unroll
            for (int mi = 0; mi < MR; ++mi) {
                int rbase = m0 + wr * WM + mi * 32 + 4 * lh;
#pragma unroll
                for (int reg = 0; reg < 16; ++reg) {
                    int row = rbase + (reg & 3) + 8 * (reg >> 2);
                    C[(size_t)row * ldC + col] = acc[mi][ni][reg] + bv;
                }
            }
        }
    }
}

// ---------------------------------------------------------------- MFMA flash attention (+fused RoPE)
// qkv holds RAW (bias-added, un-roped) q,k,v. RoPE applied here in f32 during bf16 convert.
__global__ __launch_bounds__(512) void attn_mfma_kernel(
    const float* __restrict__ qkv, const float* __restrict__ sinks,
    const float* __restrict__ cosp, const float* __restrict__ sinp,
    ushort* __restrict__ attn_out)
{
    __shared__ __align__(16) ushort Kl[160][72];    // [key][d], pad 64->72 (2-way free)
    __shared__ __align__(16) ushort Vt[64][168];    // [d][key], pad 160->168 (2-way free)
    __shared__ __align__(16) ushort Pl[8][32][40];  // per-wave P chunk [row][32 keys], pad->40
    const int t = threadIdx.x;
    const int w = t >> 6;
    const int l = t & 63;
    const int g4 = l >> 4;
    const int r15 = l & 15;
    const int q0 = blockIdx.x * 32;
    const int hk = blockIdx.y;
    const int kbase = q0 - 128;

    // ---- stage K (rope'd) [160][64] f32->bf16 and V^T [64][160]
#pragma unroll
    for (int i = 0; i < 5; ++i) {
        int idx = i * 512 + t;             // 0..2559
        int row = idx >> 4;                // 0..159
        int c4 = (idx & 15) * 4;           // 0..60
        int j = kbase + row;
        float4 kr = make_float4(0.f, 0.f, 0.f, 0.f);
        float4 vv = make_float4(0.f, 0.f, 0.f, 0.f);
        if (j >= 0) {
            const float* kb = &qkv[(size_t)j * QKV_N + 4096 + hk * 64];
            float4 kx = *(const float4*)&kb[c4];
            float4 ky = *(const float4*)&kb[c4 ^ 32];
            float4 cs = *(const float4*)&cosp[j * 32 + (c4 & 31)];
            float4 sn = *(const float4*)&sinp[j * 32 + (c4 & 31)];
            if (c4 < 32) {
                kr.x = kx.x * cs.x - ky.x * sn.x; kr.y = kx.y * cs.y - ky.y * sn.y;
                kr.z = kx.z * cs.z - ky.z * sn.z; kr.w = kx.w * cs.w - ky.w * sn.w;
            } else {
                kr.x = kx.x * cs.x + ky.x * sn.x; kr.y = kx.y * cs.y + ky.y * sn.y;
                kr.z = kx.z * cs.z + ky.z * sn.z; kr.w = kx.w * cs.w + ky.w * sn.w;
            }
            vv = *(const float4*)&qkv[(size_t)j * QKV_N + 4608 + hk * 64 + c4];
        }
        ushort4 kp;
        kp.x = f2bf(kr.x); kp.y = f2bf(kr.y); kp.z = f2bf(kr.z); kp.w = f2bf(kr.w);
        *(ushort4*)&Kl[row][c4] = kp;
        Vt[c4 + 0][row] = f2bf(vv.x);
        Vt[c4 + 1][row] = f2bf(vv.y);
        Vt[c4 + 2][row] = f2bf(vv.z);
        Vt[c4 + 3][row] = f2bf(vv.w);
    }

    // ---- Q fragments, rope'd (B operand: lane supplies col = score-row = r15+16ct, k = d)
    bf16x8 qf[2][2];
#pragma unroll
    for (int ct = 0; ct < 2; ++ct) {
        int R = w * 32 + ct * 16 + r15;
        int q = q0 + (R & 31);
        int hq = hk * 8 + (R >> 5);
        const float* qb = &qkv[(size_t)q * QKV_N + hq * 64];
        int d8 = g4 * 8;                       // 0,8,16,24 (first-half base)
        float4 a0 = *(const float4*)&qb[d8];          // s=0 lo
        float4 b0 = *(const float4*)&qb[d8 + 4];      // s=0 hi
        float4 a1 = *(const float4*)&qb[32 + d8];     // s=1 lo
        float4 b1 = *(const float4*)&qb[32 + d8 + 4]; // s=1 hi
        float4 c0 = *(const float4*)&cosp[q * 32 + d8];
        float4 c1 = *(const float4*)&cosp[q * 32 + d8 + 4];
        float4 s0 = *(const float4*)&sinp[q * 32 + d8];
        float4 s1 = *(const float4*)&sinp[q * 32 + d8 + 4];
        union { ushort u[8]; bf16x8 v; } p0, p1;
        p0.u[0] = f2bf((a0.x * c0.x - a1.x * s0.x) * SCALE_F);
        p0.u[1] = f2bf((a0.y * c0.y - a1.y * s0.y) * SCALE_F);
        p0.u[2] = f2bf((a0.z * c0.z - a1.z * s0.z) * SCALE_F);
        p0.u[3] = f2bf((a0.w * c0.w - a1.w * s0.w) * SCALE_F);
        p0.u[4] = f2bf((b0.x * c1.x - b1.x * s1.x) * SCALE_F);
        p0.u[5] = f2bf((b0.y * c1.y - b1.y * s1.y) * SCALE_F);
        p0.u[6] = f2bf((b0.z * c1.z - b1.z * s1.z) * SCALE_F);
        p0.u[7] = f2bf((b0.w * c1.w - b1.w * s1.w) * SCALE_F);
        p1.u[0] = f2bf((a1.x * c0.x + a0.x * s0.x) * SCALE_F);
        p1.u[1] = f2bf((a1.y * c0.y + a0.y * s0.y) * SCALE_F);
        p1.u[2] = f2bf((a1.z * c0.z + a0.z * s0.z) * SCALE_F);
        p1.u[3] = f2bf((a1.w * c0.w + a0.w * s0.w) * SCALE_F);
        p1.u[4] = f2bf((b1.x * c1.x + b0.x * s1.x) * SCALE_F);
        p1.u[5] = f2bf((b1.y * c1.y + b0.y * s1.y) * SCALE_F);
        p1.u[6] = f2bf((b1.z * c1.z + b0.z * s1.z) * SCALE_F);
        p1.u[7] = f2bf((b1.w * c1.w + b0.w * s1.w) * SCALE_F);
        qf[ct][0] = p0.v;
        qf[ct][1] = p1.v;
    }
    __syncthreads();

    // ---- S^T = K @ Q^T : D row = key = 16kt+4g4+r, col = score-row = 16ct+r15 (+32w)
    f32x4 sc[10][2];
#pragma unroll
    for (int kt = 0; kt < 10; ++kt) {
        sc[kt][0] = (f32x4){0.f, 0.f, 0.f, 0.f};
        sc[kt][1] = (f32x4){0.f, 0.f, 0.f, 0.f};
    }
#pragma unroll
    for (int kt = 0; kt < 10; ++kt) {
#pragma unroll
        for (int s = 0; s < 2; ++s) {
            bf16x8 kf = *(const bf16x8*)&Kl[kt * 16 + r15][s * 32 + g4 * 8];
            sc[kt][0] = __builtin_amdgcn_mfma_f32_16x16x32_bf16(kf, qf[0][s], sc[kt][0], 0, 0, 0);
            sc[kt][1] = __builtin_amdgcn_mfma_f32_16x16x32_bf16(kf, qf[1][s], sc[kt][1], 0, 0, 0);
        }
    }

    // ---- masked softmax, per score-row; fold sink and 1/denom (all lane-local)
    const int minkey = 128 - q0;          // key_local >= minkey  <=>  j >= 0
#pragma unroll
    for (int ct = 0; ct < 2; ++ct) {
        int R = w * 32 + ct * 16 + r15;
        int ql = R & 31;
        float snk = sinks[hk * 8 + (R >> 5)];
#pragma unroll
        for (int kt = 0; kt < 10; ++kt)
#pragma unroll
            for (int r = 0; r < 4; ++r) {
                int key = kt * 16 + g4 * 4 + r;
                // allowed: q_local < key <= q_local+128 (window+causal), key >= minkey (j>=0)
                bool ok = (key > ql) && (key <= ql + 128) && (key >= minkey);
                if (!ok) sc[kt][ct][r] = -1e30f;
            }
        float m = snk;
#pragma unroll
        for (int kt = 0; kt < 10; ++kt)
#pragma unroll
            for (int r = 0; r < 4; ++r) m = fmaxf(m, sc[kt][ct][r]);
        m = fmaxf(m, __shfl_xor(m, 16));
        m = fmaxf(m, __shfl_xor(m, 32));
        float sum = 0.f;
#pragma unroll
        for (int kt = 0; kt < 10; ++kt)
#pragma unroll
            for (int r = 0; r < 4; ++r) {
                float p = __expf(sc[kt][ct][r] - m);
                sc[kt][ct][r] = p;
                sum += p;
            }
        sum += __shfl_xor(sum, 16);
        sum += __shfl_xor(sum, 32);
        sum += __expf(snk - m);
        float iv = 1.0f / sum;
#pragma unroll
        for (int kt = 0; kt < 10; ++kt)
#pragma unroll
            for (int r = 0; r < 4; ++r) sc[kt][ct][r] *= iv;
    }

    // ---- PV: out[row][d] = sum_key P[row][key] * V[key][d]
    f32x4 pv[2][4];
#pragma unroll
    for (int mi = 0; mi < 2; ++mi)
#pragma unroll
        for (int ni = 0; ni < 4; ++ni) pv[mi][ni] = (f32x4){0.f, 0.f, 0.f, 0.f};

#pragma unroll
    for (int s = 0; s < 5; ++s) {
#pragma unroll
        for (int ct = 0; ct < 2; ++ct)
#pragma unroll
            for (int kh = 0; kh < 2; ++kh) {
                int kt = 2 * s + kh;
                ushort4 p4;
                p4.x = f2bf(sc[kt][ct][0]);
                p4.y = f2bf(sc[kt][ct][1]);
                p4.z = f2bf(sc[kt][ct][2]);
                p4.w = f2bf(sc[kt][ct][3]);
                *(ushort4*)&Pl[w][ct * 16 + r15][kh * 16 + g4 * 4] = p4;
            }
#pragma unroll
        for (int mi = 0; mi < 2; ++mi) {
            bf16x8 pf = *(const bf16x8*)&Pl[w][mi * 16 + r15][g4 * 8];
#pragma unroll
            for (int ni = 0; ni < 4; ++ni) {
                bf16x8 vf = *(const bf16x8*)&Vt[ni * 16 + r15][s * 32 + g4 * 8];
                pv[mi][ni] = __builtin_amdgcn_mfma_f32_16x16x32_bf16(pf, vf, pv[mi][ni], 0, 0, 0);
            }
        }
    }

    // ---- write attn output (bf16): D row = 16mi+4g4+r (+32w), col = d = 16ni+r15
#pragma unroll
    for (int mi = 0; mi < 2; ++mi)
#pragma unroll
        for (int r = 0; r < 4; ++r) {
            int R = w * 32 + mi * 16 + g4 * 4 + r;
            int q = q0 + (R & 31);
            int hq = hk * 8 + (R >> 5);
            ushort* ob = &attn_out[(size_t)q * ATTN_N + hq * 64 + r15];
#pragma unroll
            for (int ni = 0; ni < 4; ++ni)
                ob[ni * 16] = f2bf(pv[mi][ni][r]);
        }
}

// ---------------------------------------------------------------- launch
extern "C" void kernel_launch(void* const* d_in, const int* in_sizes, int n_in,
                              void* d_out, int out_size, void* d_ws, size_t ws_size,
                              hipStream_t stream)
{
    const float* hidden = (const float*)d_in[0];
    const float* cosp   = (const float*)d_in[1];
    const float* sinp   = (const float*)d_in[2];
    const float* w_qkv  = (const float*)d_in[3];
    const float* b_qkv  = (const float*)d_in[4];
    const float* w_o    = (const float*)d_in[5];
    const float* b_o    = (const float*)d_in[6];
    const float* sinks  = (const float*)d_in[7];
    // d_in[8]=k_cache, d_in[9]=v_cache (zero), d_in[10]=kv_len (==0): unused.

    char* ws = (char*)d_ws;
    size_t off = 0;
    ushort* wqkvT = (ushort*)(ws + off); off += (size_t)QKV_N * HID * 2;      // [5120][2880]
    ushort* woT   = (ushort*)(ws + off); off += (size_t)WO_NPAD * ATTN_N * 2; // [2880][4096]
    float*  qkv   = (float*)(ws + off);  off += (size_t)SEQ * QKV_N * 4;
    // union region: hidden_b (gemm1 A) then attn_b (gemm2 A) — lifetimes disjoint
    ushort* hidden_b = (ushort*)(ws + off);
    ushort* attn_b   = (ushort*)(ws + off); off += (size_t)SEQ * ATTN_N * 2;
    if (off > ws_size) return;  // fail visibly rather than corrupt

    // weight transposes + hidden convert
    transpose_convert<<<dim3(HID / 64, QKV_N / 64), 256, 0, stream>>>(w_qkv, wqkvT, HID, QKV_N);
    transpose_convert<<<dim3(ATTN_N / 64, WO_NPAD / 64), 256, 0, stream>>>(w_o, woT, ATTN_N, HID);
    convert_f32_bf16<<<2048, 256, 0, stream>>>(hidden, hidden_b, SEQ * HID / 4);

    // QKV projection (rope deferred to attention). Tile 128x128, grid 40x8 = 320.
    gemm32<128, 128, 2><<<dim3(QKV_N / 128, SEQ / 128), 512, 0, stream>>>(
        hidden_b, wqkvT, b_qkv, qkv, HID, QKV_N, QKV_N);

    // MFMA flash attention with fused RoPE on Q and K
    attn_mfma_kernel<<<dim3(SEQ / 32, NKVH), 512, 0, stream>>>(
        qkv, sinks, cosp, sinp, attn_b);

    // output projection. Tile 128x64, grid 45x8 = 360. 2880 = 45*64 exactly.
    gemm32<128, 64, 2><<<dim3(HID / 64, SEQ / 128), 512, 0, stream>>>(
        attn_b, woT, b_o, (float*)d_out, ATTN_N, HID, HID);
}

// Round 19
// 137.300 us; speedup vs baseline: 1.1102x; 1.0953x over previous
//
#include <hip/hip_runtime.h>
#include <hip/hip_bf16.h>

#define NQH 64
#define NKVH 8
#define DH 64
#define SEQ 1024
#define HID 2880
#define QKV_N 5120   // (NQ+2*NKV)*DH
#define ATTN_N 4096  // NQ*DH
#define WIN 128
#define WO_NPAD 3072 // 32*96 (zero-padded rows 2880..3071)
#define SCALE_F 0.125f

typedef __attribute__((ext_vector_type(8))) __bf16 bf16x8;
typedef __attribute__((ext_vector_type(4))) float f32x4;

#define GLOAD_LDS16(g, l) \
    __builtin_amdgcn_global_load_lds((const __attribute__((address_space(1))) void*)(g), \
                                     (__attribute__((address_space(3))) void*)(l), 16, 0, 0)

__device__ __forceinline__ ushort f2bf(float x) {
    union { float f; unsigned int u; } c; c.f = x;
    unsigned int u = c.u;
    unsigned int r = (u + 0x7FFFu + ((u >> 16) & 1u)) >> 16;
    return (ushort)r;
}

__device__ __forceinline__ float bf2f(ushort u) {
    union { unsigned int u; float f; } c;
    c.u = ((unsigned int)u) << 16;
    return c.f;
}

// ---------------------------------------------------------------- convert (plain)
__global__ __launch_bounds__(256) void convert_f32_bf16(
    const float* __restrict__ in, ushort* __restrict__ out, int n4)
{
    int idx = blockIdx.x * blockDim.x + threadIdx.x;
    int stride = gridDim.x * blockDim.x;
    for (int i = idx; i < n4; i += stride) {
        float4 v = reinterpret_cast<const float4*>(in)[i];
        ushort4 o;
        o.x = f2bf(v.x); o.y = f2bf(v.y); o.z = f2bf(v.z); o.w = f2bf(v.w);
        reinterpret_cast<ushort4*>(out)[i] = o;
    }
}

// ---------------------------------------------------------------- transpose+convert
// in: [K][N] f32  ->  out: [Npad][K] bf16 (rows >= N zero-filled). K,Npad multiples of 64.
__global__ __launch_bounds__(256) void transpose_convert(
    const float* __restrict__ in, ushort* __restrict__ out, int K, int N)
{
    __shared__ ushort tile[64][80];   // row stride 160B (16B-aligned for uint4)
    const int bk = blockIdx.x * 64;   // k tile origin
    const int bn = blockIdx.y * 64;   // n tile origin
    const int tid = threadIdx.x;
    const bool inb = bn < N;          // whole tile valid or whole tile pad (N % 64 == 0)

#pragma unroll
    for (int it = 0; it < 4; ++it) {
        int r = it * 16 + (tid >> 4);         // k offset 0..63
        int c4 = (tid & 15) * 4;              // n offset
        float4 v = make_float4(0.f, 0.f, 0.f, 0.f);
        if (inb) v = *(const float4*)&in[(size_t)(bk + r) * N + bn + c4];
        tile[c4 + 0][r] = f2bf(v.x);
        tile[c4 + 1][r] = f2bf(v.y);
        tile[c4 + 2][r] = f2bf(v.z);
        tile[c4 + 3][r] = f2bf(v.w);
    }
    __syncthreads();
#pragma unroll
    for (int it = 0; it < 2; ++it) {
        int nr = it * 32 + (tid >> 3);        // n offset 0..63
        int c8 = (tid & 7) * 8;               // k offset
        uint4 v = *(const uint4*)&tile[nr][c8];
        *(uint4*)&out[(size_t)(bn + nr) * K + bk + c8] = v;
    }
}

// ---------------------------------------------------------------- balanced-grid GEMM, BK=64 (R13)
// A: [M][K] bf16, BT: [Npad][K] bf16, C: [M][ldC] f32 or bf16 (+bias), K % 64 == 0.
// R13-R18 conclusion: with M=1024, 2 blocks/CU <=> 512 blocks <=> BM*BN = 10240, and all
// MFMA-tileable factorizations land at 93-95 B/KFLOP LDS-port traffic -> these tiles are
// the constrained optimum (measured within 2% of the 93 B/cyc/CU port model).
// gemm1 128x80 (64x8 grid), gemm2 64x96 (32x16 grid, Npad 3072).
// R5 dbuf sync (counted variants equivalent); swizzle slot = chunk ^ (row&7) (0 conflicts).
template<int BM, int BN, int WAVES_N, bool BF16OUT>
__global__ __launch_bounds__(512) void gemm_bal(
    const ushort* __restrict__ A, const ushort* __restrict__ BT,
    const float* __restrict__ bias, void* __restrict__ Cout,
    int K, int ldC, int Nreal)
{
    constexpr int WAVES_M = 8 / WAVES_N;
    constexpr int WM = BM / WAVES_M;
    constexpr int WN = BN / WAVES_N;
    constexpr int MR = WM / 16;
    constexpr int NR = WN / 16;
    constexpr int ASZ = BM * 64;          // elements per buffer
    constexpr int BSZ = BN * 64;
    constexpr int ACH = BM * 8;           // 16B chunks in A tile
    constexpr int TOTCH = (BM + BN) * 8;
    constexpr int NLOAD = (TOTCH + 511) / 512;

    __shared__ ushort Al[2 * ASZ];
    __shared__ ushort Bl[2 * BSZ];

    const int t = threadIdx.x;
    const int lane = t & 63;
    const int w = t >> 6;
    const int wr = w / WAVES_N;
    const int wc = w % WAVES_N;
    const int g4 = lane >> 4;
    const int r15 = lane & 15;

    // bijective XCD swizzle (nwg = 512, % 8 == 0); n-tiles walk fastest within an XCD
    const int nx = gridDim.x;
    const int flat = blockIdx.x + nx * blockIdx.y;
    const int per = (nx * gridDim.y) >> 3;
    const int virt = (flat & 7) * per + (flat >> 3);
    const int n0 = (virt % nx) * BN;
    const int m0 = (virt / nx) * BM;

    // ---- staging tables (inverse-swizzled global source, linear LDS dest)
    const ushort* src[NLOAD];
    ushort* d0[NLOAD];
    ushort* d1[NLOAD];
#pragma unroll
    for (int i = 0; i < NLOAD; ++i) {
        int lin = i * 512 + t;
        src[i] = nullptr; d0[i] = nullptr; d1[i] = nullptr;
        if (lin < ACH) {
            int row = lin >> 3, ch = (lin & 7) ^ (row & 7);
            src[i] = A + (size_t)(m0 + row) * K + ch * 8;
            d0[i] = &Al[lin * 8];
            d1[i] = &Al[ASZ + lin * 8];
        } else if (lin < TOTCH) {
            int l2 = lin - ACH;
            int row = l2 >> 3, ch = (l2 & 7) ^ (row & 7);
            src[i] = BT + (size_t)(n0 + row) * K + ch * 8;
            d0[i] = &Bl[l2 * 8];
            d1[i] = &Bl[BSZ + l2 * 8];
        }
    }

#define STAGE_TILE(buf) do { \
        _Pragma("unroll") \
        for (int i = 0; i < NLOAD; ++i) \
            if (src[i]) { \
                GLOAD_LDS16(src[i], (buf) ? d1[i] : d0[i]); \
                src[i] += 64; \
            } \
    } while (0)

    // ---- fragment read offsets (element units), swizzled to match staging
    int aoff[MR][2], boff[NR][2];
#pragma unroll
    for (int mi = 0; mi < MR; ++mi)
#pragma unroll
        for (int ks = 0; ks < 2; ++ks) {
            int row = wr * WM + mi * 16 + r15;
            aoff[mi][ks] = row * 64 + (((ks * 4 + g4) ^ (row & 7)) * 8);
        }
#pragma unroll
    for (int ni = 0; ni < NR; ++ni)
#pragma unroll
        for (int ks = 0; ks < 2; ++ks) {
            int col = wc * WN + ni * 16 + r15;
            boff[ni][ks] = col * 64 + (((ks * 4 + g4) ^ (col & 7)) * 8);
        }

    f32x4 acc[MR][NR];
#pragma unroll
    for (int mi = 0; mi < MR; ++mi)
#pragma unroll
        for (int ni = 0; ni < NR; ++ni) acc[mi][ni] = (f32x4){0.f, 0.f, 0.f, 0.f};

#define COMPUTE_TILE(buf) do { \
        const ushort* Ab = &Al[(buf) * ASZ]; \
        const ushort* Bb = &Bl[(buf) * BSZ]; \
        _Pragma("unroll") \
        for (int ks = 0; ks < 2; ++ks) { \
            bf16x8 af[MR], bfr[NR]; \
            _Pragma("unroll") \
            for (int mi = 0; mi < MR; ++mi) af[mi] = *(const bf16x8*)&Ab[aoff[mi][ks]]; \
            _Pragma("unroll") \
            for (int ni = 0; ni < NR; ++ni) bfr[ni] = *(const bf16x8*)&Bb[boff[ni][ks]]; \
            _Pragma("unroll") \
            for (int mi = 0; mi < MR; ++mi) \
                _Pragma("unroll") \
                for (int ni = 0; ni < NR; ++ni) \
                    acc[mi][ni] = __builtin_amdgcn_mfma_f32_16x16x32_bf16(af[mi], bfr[ni], acc[mi][ni], 0, 0, 0); \
        } \
    } while (0)

    const int NT = K >> 6;
    STAGE_TILE(0);
    __syncthreads();                            // tile 0 ready
    for (int kt = 0; kt < NT; kt += 2) {
        if (kt + 1 < NT) STAGE_TILE(1);         // prefetch next before compute
        COMPUTE_TILE(0);
        __syncthreads();
        if (kt + 1 < NT) {
            if (kt + 2 < NT) STAGE_TILE(0);
            COMPUTE_TILE(1);
            __syncthreads();
        }
    }
#undef STAGE_TILE
#undef COMPUTE_TILE

    // ---- epilogue: bias, f32 or bf16 store (rope fused into attention)
    // D frag: row = g4*4 + r (+16*mi +WM*wr +m0), col = r15 (+16*ni +WN*wc +n0)
#pragma unroll
    for (int ni = 0; ni < NR; ++ni) {
        int col = n0 + wc * WN + ni * 16 + r15;
        if (col < Nreal) {
            float bv = bias[col];
#pragma unroll
            for (int mi = 0; mi < MR; ++mi) {
                int row = m0 + wr * WM + mi * 16 + g4 * 4;
#pragma unroll
                for (int r = 0; r < 4; ++r) {
                    float v = acc[mi][ni][r] + bv;
                    if (BF16OUT)
                        ((ushort*)Cout)[(size_t)(row + r) * ldC + col] = f2bf(v);
                    else
                        ((float*)Cout)[(size_t)(row + r) * ldC + col] = v;
                }
            }
        }
    }
}

// ---------------------------------------------------------------- MFMA flash attention (+fused RoPE)
// qkv holds RAW bf16 (bias-added, un-roped) q,k,v. RoPE applied in f32 at load time.
__global__ __launch_bounds__(512) void attn_mfma_kernel(
    const ushort* __restrict__ qkv, const float* __restrict__ sinks,
    const float* __restrict__ cosp, const float* __restrict__ sinp,
    ushort* __restrict__ attn_out)
{
    __shared__ __align__(16) ushort Kl[160][72];    // [key][d], pad 64->72 (2-way free)
    __shared__ __align__(16) ushort Vt[64][168];    // [d][key], pad 160->168 (2-way free)
    __shared__ __align__(16) ushort Pl[8][32][40];  // per-wave P chunk [row][32 keys], pad->40
    const int t = threadIdx.x;
    const int w = t >> 6;
    const int l = t & 63;
    const int g4 = l >> 4;
    const int r15 = l & 15;
    const int q0 = blockIdx.x * 32;
    const int hk = blockIdx.y;
    const int kbase = q0 - 128;

    // ---- stage K (rope'd in f32) [160][64] and V^T [64][160] (V copied as-is, bf16)
#pragma unroll
    for (int i = 0; i < 5; ++i) {
        int idx = i * 512 + t;             // 0..2559
        int row = idx >> 4;                // 0..159
        int c4 = (idx & 15) * 4;           // 0..60
        int j = kbase + row;
        ushort4 kp = make_ushort4(0, 0, 0, 0);
        ushort4 vp = make_ushort4(0, 0, 0, 0);
        if (j >= 0) {
            const ushort* kb = &qkv[(size_t)j * QKV_N + 4096 + hk * 64];
            ushort4 kxu = *(const ushort4*)&kb[c4];
            ushort4 kyu = *(const ushort4*)&kb[c4 ^ 32];
            float4 cs = *(const float4*)&cosp[j * 32 + (c4 & 31)];
            float4 sn = *(const float4*)&sinp[j * 32 + (c4 & 31)];
            float kx0 = bf2f(kxu.x), kx1 = bf2f(kxu.y), kx2 = bf2f(kxu.z), kx3 = bf2f(kxu.w);
            float ky0 = bf2f(kyu.x), ky1 = bf2f(kyu.y), ky2 = bf2f(kyu.z), ky3 = bf2f(kyu.w);
            float r0, r1, r2, r3;
            if (c4 < 32) {
                r0 = kx0 * cs.x - ky0 * sn.x; r1 = kx1 * cs.y - ky1 * sn.y;
                r2 = kx2 * cs.z - ky2 * sn.z; r3 = kx3 * cs.w - ky3 * sn.w;
            } else {
                r0 = kx0 * cs.x + ky0 * sn.x; r1 = kx1 * cs.y + ky1 * sn.y;
                r2 = kx2 * cs.z + ky2 * sn.z; r3 = kx3 * cs.w + ky3 * sn.w;
            }
            kp.x = f2bf(r0); kp.y = f2bf(r1); kp.z = f2bf(r2); kp.w = f2bf(r3);
            vp = *(const ushort4*)&qkv[(size_t)j * QKV_N + 4608 + hk * 64 + c4];
        }
        *(ushort4*)&Kl[row][c4] = kp;
        Vt[c4 + 0][row] = vp.x;
        Vt[c4 + 1][row] = vp.y;
        Vt[c4 + 2][row] = vp.z;
        Vt[c4 + 3][row] = vp.w;
    }

    // ---- Q fragments, rope'd (B operand: lane supplies col = score-row = r15+16ct, k = d)
    bf16x8 qf[2][2];
#pragma unroll
    for (int ct = 0; ct < 2; ++ct) {
        int R = w * 32 + ct * 16 + r15;
        int q = q0 + (R & 31);
        int hq = hk * 8 + (R >> 5);
        const ushort* qb = &qkv[(size_t)q * QKV_N + hq * 64];
        int d8 = g4 * 8;                       // 0,8,16,24 (first-half base)
        ushort4 q0a = *(const ushort4*)&qb[d8];           // s=0, d8..d8+3
        ushort4 q0b = *(const ushort4*)&qb[d8 + 4];       // s=0, d8+4..d8+7
        ushort4 q1a = *(const ushort4*)&qb[32 + d8];      // s=1
        ushort4 q1b = *(const ushort4*)&qb[32 + d8 + 4];
        float4 c0 = *(const float4*)&cosp[q * 32 + d8];
        float4 c1 = *(const float4*)&cosp[q * 32 + d8 + 4];
        float4 s0 = *(const float4*)&sinp[q * 32 + d8];
        float4 s1 = *(const float4*)&sinp[q * 32 + d8 + 4];
        float x0[8], x1[8];
        x0[0] = bf2f(q0a.x); x0[1] = bf2f(q0a.y); x0[2] = bf2f(q0a.z); x0[3] = bf2f(q0a.w);
        x0[4] = bf2f(q0b.x); x0[5] = bf2f(q0b.y); x0[6] = bf2f(q0b.z); x0[7] = bf2f(q0b.w);
        x1[0] = bf2f(q1a.x); x1[1] = bf2f(q1a.y); x1[2] = bf2f(q1a.z); x1[3] = bf2f(q1a.w);
        x1[4] = bf2f(q1b.x); x1[5] = bf2f(q1b.y); x1[6] = bf2f(q1b.z); x1[7] = bf2f(q1b.w);
        float cc[8] = {c0.x, c0.y, c0.z, c0.w, c1.x, c1.y, c1.z, c1.w};
        float ss[8] = {s0.x, s0.y, s0.z, s0.w, s1.x, s1.y, s1.z, s1.w};
        union { ushort u[8]; bf16x8 v; } p0, p1;
#pragma unroll
        for (int i = 0; i < 8; ++i) {
            p0.u[i] = f2bf((x0[i] * cc[i] - x1[i] * ss[i]) * SCALE_F);
            p1.u[i] = f2bf((x1[i] * cc[i] + x0[i] * ss[i]) * SCALE_F);
        }
        qf[ct][0] = p0.v;
        qf[ct][1] = p1.v;
    }
    __syncthreads();

    // ---- S^T = K @ Q^T : D row = key = 16kt+4g4+r, col = score-row = 16ct+r15 (+32w)
    f32x4 sc[10][2];
#pragma unroll
    for (int kt = 0; kt < 10; ++kt) {
        sc[kt][0] = (f32x4){0.f, 0.f, 0.f, 0.f};
        sc[kt][1] = (f32x4){0.f, 0.f, 0.f, 0.f};
    }
#pragma unroll
    for (int kt = 0; kt < 10; ++kt) {
#pragma unroll
        for (int s = 0; s < 2; ++s) {
            bf16x8 kf = *(const bf16x8*)&Kl[kt * 16 + r15][s * 32 + g4 * 8];
            sc[kt][0] = __builtin_amdgcn_mfma_f32_16x16x32_bf16(kf, qf[0][s], sc[kt][0], 0, 0, 0);
            sc[kt][1] = __builtin_amdgcn_mfma_f32_16x16x32_bf16(kf, qf[1][s], sc[kt][1], 0, 0, 0);
        }
    }

    // ---- masked softmax, per score-row; fold sink and 1/denom (all lane-local)
    const int minkey = 128 - q0;          // key_local >= minkey  <=>  j >= 0
#pragma unroll
    for (int ct = 0; ct < 2; ++ct) {
        int R = w * 32 + ct * 16 + r15;
        int ql = R & 31;
        float snk = sinks[hk * 8 + (R >> 5)];
#pragma unroll
        for (int kt = 0; kt < 10; ++kt)
#pragma unroll
            for (int r = 0; r < 4; ++r) {
                int key = kt * 16 + g4 * 4 + r;
                // allowed: q_local < key <= q_local+128 (window+causal), key >= minkey (j>=0)
                bool ok = (key > ql) && (key <= ql + 128) && (key >= minkey);
                if (!ok) sc[kt][ct][r] = -1e30f;
            }
        float m = snk;
#pragma unroll
        for (int kt = 0; kt < 10; ++kt)
#pragma unroll
            for (int r = 0; r < 4; ++r) m = fmaxf(m, sc[kt][ct][r]);
        m = fmaxf(m, __shfl_xor(m, 16));
        m = fmaxf(m, __shfl_xor(m, 32));
        float sum = 0.f;
#pragma unroll
        for (int kt = 0; kt < 10; ++kt)
#pragma unroll
            for (int r = 0; r < 4; ++r) {
                float p = __expf(sc[kt][ct][r] - m);
                sc[kt][ct][r] = p;
                sum += p;
            }
        sum += __shfl_xor(sum, 16);
        sum += __shfl_xor(sum, 32);
        sum += __expf(snk - m);
        float iv = 1.0f / sum;
#pragma unroll
        for (int kt = 0; kt < 10; ++kt)
#pragma unroll
            for (int r = 0; r < 4; ++r) sc[kt][ct][r] *= iv;
    }

    // ---- PV: out[row][d] = sum_key P[row][key] * V[key][d]
    f32x4 pv[2][4];
#pragma unroll
    for (int mi = 0; mi < 2; ++mi)
#pragma unroll
        for (int ni = 0; ni < 4; ++ni) pv[mi][ni] = (f32x4){0.f, 0.f, 0.f, 0.f};

#pragma unroll
    for (int s = 0; s < 5; ++s) {
#pragma unroll
        for (int ct = 0; ct < 2; ++ct)
#pragma unroll
            for (int kh = 0; kh < 2; ++kh) {
                int kt = 2 * s + kh;
                ushort4 p4;
                p4.x = f2bf(sc[kt][ct][0]);
                p4.y = f2bf(sc[kt][ct][1]);
                p4.z = f2bf(sc[kt][ct][2]);
                p4.w = f2bf(sc[kt][ct][3]);
                *(ushort4*)&Pl[w][ct * 16 + r15][kh * 16 + g4 * 4] = p4;
            }
#pragma unroll
        for (int mi = 0; mi < 2; ++mi) {
            bf16x8 pf = *(const bf16x8*)&Pl[w][mi * 16 + r15][g4 * 8];
#pragma unroll
            for (int ni = 0; ni < 4; ++ni) {
                bf16x8 vf = *(const bf16x8*)&Vt[ni * 16 + r15][s * 32 + g4 * 8];
                pv[mi][ni] = __builtin_amdgcn_mfma_f32_16x16x32_bf16(pf, vf, pv[mi][ni], 0, 0, 0);
            }
        }
    }

    // ---- write attn output (bf16): D row = 16mi+4g4+r (+32w), col = d = 16ni+r15
#pragma unroll
    for (int mi = 0; mi < 2; ++mi)
#pragma unroll
        for (int r = 0; r < 4; ++r) {
            int R = w * 32 + mi * 16 + g4 * 4 + r;
            int q = q0 + (R & 31);
            int hq = hk * 8 + (R >> 5);
            ushort* ob = &attn_out[(size_t)q * ATTN_N + hq * 64 + r15];
#pragma unroll
            for (int ni = 0; ni < 4; ++ni)
                ob[ni * 16] = f2bf(pv[mi][ni][r]);
        }
}

// ---------------------------------------------------------------- launch
extern "C" void kernel_launch(void* const* d_in, const int* in_sizes, int n_in,
                              void* d_out, int out_size, void* d_ws, size_t ws_size,
                              hipStream_t stream)
{
    const float* hidden = (const float*)d_in[0];
    const float* cosp   = (const float*)d_in[1];
    const float* sinp   = (const float*)d_in[2];
    const float* w_qkv  = (const float*)d_in[3];
    const float* b_qkv  = (const float*)d_in[4];
    const float* w_o    = (const float*)d_in[5];
    const float* b_o    = (const float*)d_in[6];
    const float* sinks  = (const float*)d_in[7];
    // d_in[8]=k_cache, d_in[9]=v_cache (zero), d_in[10]=kv_len (==0): unused.

    char* ws = (char*)d_ws;
    size_t off = 0;
    ushort* wqkvT = (ushort*)(ws + off); off += (size_t)QKV_N * HID * 2;      // [5120][2880]
    ushort* woT   = (ushort*)(ws + off); off += (size_t)WO_NPAD * ATTN_N * 2; // [3072][4096]
    ushort* qkv   = (ushort*)(ws + off); off += (size_t)SEQ * QKV_N * 2;      // bf16 now
    // union region: hidden_b (gemm1 A) then attn_b (gemm2 A) — lifetimes disjoint
    ushort* hidden_b = (ushort*)(ws + off);
    ushort* attn_b   = (ushort*)(ws + off); off += (size_t)SEQ * ATTN_N * 2;
    if (off > ws_size) return;  // fail visibly rather than corrupt

    // weight transposes + hidden convert
    transpose_convert<<<dim3(HID / 64, QKV_N / 64), 256, 0, stream>>>(w_qkv, wqkvT, HID, QKV_N);
    transpose_convert<<<dim3(ATTN_N / 64, WO_NPAD / 64), 256, 0, stream>>>(w_o, woT, ATTN_N, HID);
    convert_f32_bf16<<<2048, 256, 0, stream>>>(hidden, hidden_b, SEQ * HID / 4);

    // QKV projection -> bf16 qkv (rope deferred). Tile 128x80, grid 64x8 = 512.
    gemm_bal<128, 80, 1, true><<<dim3(QKV_N / 80, SEQ / 128), 512, 0, stream>>>(
        hidden_b, wqkvT, b_qkv, qkv, HID, QKV_N, QKV_N);

    // MFMA flash attention with fused RoPE on Q and K (bf16 qkv input)
    attn_mfma_kernel<<<dim3(SEQ / 32, NKVH), 512, 0, stream>>>(
        qkv, sinks, cosp, sinp, attn_b);

    // output projection -> f32 d_out. Tile 64x96, grid 32x16 = 512 (Npad 3072).
    gemm_bal<64, 96, 2, false><<<dim3(WO_NPAD / 96, SEQ / 64), 512, 0, stream>>>(
        attn_b, woT, b_o, d_out, ATTN_N, HID, HID);
}